// Round 1
// 425.749 us; speedup vs baseline: 1.0502x; 1.0502x over previous
//
#include <hip/hip_runtime.h>

typedef unsigned short u16;
typedef __bf16 bf16x8 __attribute__((ext_vector_type(8)));
typedef float f32x4 __attribute__((ext_vector_type(4)));

constexpr int Bq  = 4;
constexpr int Sq  = 2048;
constexpr int Hq  = 1024;
constexpr int NHq = 16;
constexpr int HDq = 64;
constexpr int CCH = 16;    // chunks
constexpr int LCH = 128;   // chunk length

// workspace layout (bytes), total 212,860,928
constexpr size_t OFF_WB = 0;             // W bf16: 5*1M*2 = 10,485,760
constexpr size_t OFF_XB = 10485760;      // 16,777,216: x-bf16 -> Qc (scan) -> y-bf16 (epilogue)
constexpr size_t OFF_Q  = 27262976;      // q fp32: 33,554,432
constexpr size_t OFF_K  = 60817408;
constexpr size_t OFF_V  = 94371840;
constexpr size_t OFF_G  = 127926272;
constexpr size_t OFF_AL = 161480704;     // alpha: 524,288
constexpr size_t OFF_BE = 162004992;
constexpr size_t OFF_P  = 162529280;     // Wab bf16 (512 KB, 256 rows) during GEMM -> chunk P (16 MB) during scan
constexpr size_t OFF_O  = 179306496;     // of fp32: 33,554,432 (end 212,860,928)

__device__ __forceinline__ u16 f2bf(float f) {
  unsigned u = __float_as_uint(f);
  u += 0x7fffu + ((u >> 16) & 1u);
  return (u16)(u >> 16);
}
__device__ __forceinline__ float sigmoidf_(float x) { return 1.f / (1.f + __expf(-x)); }

__device__ __forceinline__ void async16(const void* g, void* l) {
  __builtin_amdgcn_global_load_lds((const __attribute__((address_space(1))) void*)g,
                                   (__attribute__((address_space(3))) void*)l, 16, 0, 0);
}

// ---------------- converts ----------------
__global__ __launch_bounds__(256) void cvt_x_kernel(const float* __restrict__ in, u16* __restrict__ outp) {
  const size_t i = ((size_t)blockIdx.x * 256 + threadIdx.x) * 4;
  float4 f = *(const float4*)(in + i);
  ushort4 u; u.x = f2bf(f.x); u.y = f2bf(f.y); u.z = f2bf(f.z); u.w = f2bf(f.w);
  *(ushort4*)(outp + i) = u;
}

__global__ __launch_bounds__(256) void cvt_w_kernel(const float* __restrict__ w0, const float* __restrict__ w1,
    const float* __restrict__ w2, const float* __restrict__ w3, const float* __restrict__ w4,
    u16* __restrict__ outp) {
  const int z = blockIdx.z;
  const float* src = (z == 0) ? w0 : (z == 1) ? w1 : (z == 2) ? w2 : (z == 3) ? w3 : w4;
  const size_t i = ((size_t)blockIdx.x * 256 + threadIdx.x) * 4;
  float4 f = *(const float4*)(src + i);
  ushort4 u; u.x = f2bf(f.x); u.y = f2bf(f.y); u.z = f2bf(f.z); u.w = f2bf(f.w);
  *(ushort4*)(outp + (size_t)z * (1024 * 1024) + i) = u;
}

// Wab: 256x1024 bf16; rows 0..15 = Wa, 16..31 = Wb, rest zero (padded for 256-wide B tile)
__global__ __launch_bounds__(256) void cvt_ab_kernel(const float* __restrict__ Wa, const float* __restrict__ Wb,
    u16* __restrict__ outp) {
  const size_t i = ((size_t)blockIdx.x * 256 + threadIdx.x) * 4;
  const int row = (int)(i >> 10);
  ushort4 u;
  if (row < 32) {
    const float* src = (row < 16) ? (Wa + i) : (Wb + i - 16 * 1024);
    float4 f = *(const float4*)src;
    u.x = f2bf(f.x); u.y = f2bf(f.y); u.z = f2bf(f.z); u.w = f2bf(f.w);
  } else {
    u.x = u.y = u.z = u.w = 0;
  }
  *(ushort4*)(outp + i) = u;
}

// ============ 256x256 8-phase bf16 MFMA GEMM (T2+T3+T4+T5) with fused epilogues ============
// 512 thr = 8 waves (2M x 4N); per-wave C = 128x64; BK=64.
// LDS = 2 bufs x {A,B} x 256x64 bf16 = 128 KiB -> 1 block/CU, 2 waves/SIMD.
// T2 swizzle: 16B slot s_phys = s_log ^ (row&7); applied on the gload_lds SOURCE (linear dest)
//   and on the ds_read side -> conflict-free ds_read_b128 (8 accesses/bank = b128 minimum).
// T3/T4 staging (race-free w.r.t. the two-barriers-per-phase structure):
//   tile t: ph0 stages A-h0(t+1)->buf^1, ph1 A-h1(t+1)->buf^1, ph2 B-h0(t+2)->buf, ph3 B-h1(t+2)->buf.
//   B-halves of buf are dead after ph1's closing barrier, A-halves after ph2's -> targets legal.
//   Boundary s_waitcnt vmcnt(4): retires through A-h1(t+1), keeps B(t+2) halves (4 loads) in flight.
// T5: s_setprio(1) around each 16-MFMA cluster. Raw s_barrier everywhere (no compiler vmcnt(0) drain).

__device__ __forceinline__ void lda4(bf16x8 af[4][2], const u16* LA, int wr, int mh, int l15, int qd, int l7) {
#pragma unroll
  for (int i = 0; i < 4; ++i)
#pragma unroll
    for (int kk = 0; kk < 2; ++kk)
      af[i][kk] = *(const bf16x8*)(LA + (wr * 128 + mh * 64 + i * 16 + l15) * 64 + (((kk * 4 + qd) ^ l7) * 8));
}
__device__ __forceinline__ void ldb2(bf16x8 bf[2][2], const u16* LB, int wc, int nh, int l15, int qd, int l7) {
#pragma unroll
  for (int j = 0; j < 2; ++j)
#pragma unroll
    for (int kk = 0; kk < 2; ++kk)
      bf[j][kk] = *(const bf16x8*)(LB + (wc * 64 + nh * 32 + j * 16 + l15) * 64 + (((kk * 4 + qd) ^ l7) * 8));
}
__device__ __forceinline__ void mm16(f32x4 acc[8][4], const bf16x8 af[4][2], const bf16x8 bf[2][2], int mh, int nh) {
#pragma unroll
  for (int i = 0; i < 4; ++i)
#pragma unroll
    for (int j = 0; j < 2; ++j) {
      f32x4 c = acc[mh * 4 + i][nh * 2 + j];
      c = __builtin_amdgcn_mfma_f32_16x16x32_bf16(af[i][0], bf[j][0], c, 0, 0, 0);
      c = __builtin_amdgcn_mfma_f32_16x16x32_bf16(af[i][1], bf[j][1], c, 0, 0, 0);
      acc[mh * 4 + i][nh * 2 + j] = c;
    }
}
// stage one 128x64 half-tile (16 KB) = 2 x global_load_lds(16B) per thread; linear LDS dest,
// inverse-swizzled global source. rr = tid>>3 (row), sl8 = ((tid&7)^(rr&7))*8 (src 16B chunk), wv = tid>>6.
__device__ __forceinline__ void stageH(u16* LD, int bufp, int mat, int h, const u16* gRow0, int kElem,
                                       int rr, int sl8, int wv) {
  const u16* s0 = gRow0 + (size_t)(h * 128 + rr) * 1024 + kElem + sl8;
  u16* d = LD + bufp * 32768 + mat * 16384 + h * 8192 + wv * 512;
  async16(s0, d);
  async16(s0 + (size_t)(64 * 1024), d + 4096);
}

template<int S1, int S2, int VM>
__device__ __forceinline__ void tile16(u16* LD, int bp, int kt,
    const u16* gA, const u16* gB, f32x4 acc[8][4], bf16x8 af[4][2], bf16x8 bf0[2][2], bf16x8 bf1[2][2],
    int wr, int wc, int l15, int qd, int l7, int rr, int sl8, int wv) {
  const u16* LA = LD + bp * 32768;
  const u16* LB = LA + 16384;
  // ---- ph0: quadrant (mh0, nh0); stage A-h0(t+1)
  lda4(af, LA, wr, 0, l15, qd, l7);
  ldb2(bf0, LB, wc, 0, l15, qd, l7);
  if (S1) stageH(LD, bp ^ 1, 0, 0, gA, (kt + 1) * 64, rr, sl8, wv);
  __builtin_amdgcn_s_barrier();
  asm volatile("s_waitcnt lgkmcnt(0)" ::: "memory");
  __builtin_amdgcn_sched_barrier(0);
  __builtin_amdgcn_s_setprio(1);
  mm16(acc, af, bf0, 0, 0);
  __builtin_amdgcn_s_setprio(0);
  __builtin_amdgcn_s_barrier();
  // ---- ph1: (mh0, nh1); stage A-h1(t+1)
  ldb2(bf1, LB, wc, 1, l15, qd, l7);
  if (S1) stageH(LD, bp ^ 1, 0, 1, gA, (kt + 1) * 64, rr, sl8, wv);
  __builtin_amdgcn_s_barrier();
  asm volatile("s_waitcnt lgkmcnt(0)" ::: "memory");
  __builtin_amdgcn_sched_barrier(0);
  __builtin_amdgcn_s_setprio(1);
  mm16(acc, af, bf1, 0, 1);
  __builtin_amdgcn_s_setprio(0);
  __builtin_amdgcn_s_barrier();
  // ---- ph2: (mh1, nh0); stage B-h0(t+2)
  lda4(af, LA, wr, 1, l15, qd, l7);
  if (S2) stageH(LD, bp, 1, 0, gB, (kt + 2) * 64, rr, sl8, wv);
  __builtin_amdgcn_s_barrier();
  asm volatile("s_waitcnt lgkmcnt(0)" ::: "memory");
  __builtin_amdgcn_sched_barrier(0);
  __builtin_amdgcn_s_setprio(1);
  mm16(acc, af, bf0, 1, 0);
  __builtin_amdgcn_s_setprio(0);
  __builtin_amdgcn_s_barrier();
  // ---- ph3: (mh1, nh1); stage B-h1(t+2); boundary counted-vmcnt then barrier
  if (S2) stageH(LD, bp, 1, 1, gB, (kt + 2) * 64, rr, sl8, wv);
  __builtin_amdgcn_s_barrier();
  __builtin_amdgcn_sched_barrier(0);
  __builtin_amdgcn_s_setprio(1);
  mm16(acc, af, bf1, 1, 1);
  __builtin_amdgcn_s_setprio(0);
  if (VM == 4) asm volatile("s_waitcnt vmcnt(4)" ::: "memory");
  else if (VM == 0) asm volatile("s_waitcnt vmcnt(0)" ::: "memory");
  __builtin_amdgcn_s_barrier();
}

// mode 0: plain store to Cq (final out-proj).
// mode 1: blocks 0..31 -> alpha/beta (Wab, sigmoid+bias, wc==0 stores); blocks 32.. -> z = q,k,v,g
//         with fused l2norm/l2norm/silu/plain epilogues.
__global__ __launch_bounds__(512, 2) void gemm256(const u16* __restrict__ A, const u16* __restrict__ Wall,
    const u16* __restrict__ Wab,
    float* __restrict__ Cq, float* __restrict__ Ck, float* __restrict__ Cv, float* __restrict__ Cg,
    float* __restrict__ al, float* __restrict__ be,
    const float* __restrict__ ba, const float* __restrict__ bb, int mode) {
  __shared__ __align__(16) u16 Lds[65536];   // 128 KiB: [buf][A|B][256][64] bf16
  u16* LD = &Lds[0];
  const int tid = threadIdx.x;
  const int wv = tid >> 6, lane = tid & 63;
  const int l15 = lane & 15, qd = lane >> 4, l7 = l15 & 7;
  const int wr = wv >> 2, wc = wv & 3;
  const int rr = tid >> 3, sl8 = ((tid & 7) ^ (rr & 7)) * 8;

  int mx, ny, z;
  const u16* Wm;
  if (mode == 0) { mx = blockIdx.x & 31; ny = blockIdx.x >> 5; z = 0; Wm = Wall; }
  else if (blockIdx.x < 32) { mx = blockIdx.x; ny = 0; z = 4; Wm = Wab; }
  else {
    const int b = blockIdx.x - 32;
    mx = b & 31; ny = (b >> 5) & 3; z = b >> 7;
    Wm = Wall + (size_t)z * (1024 * 1024);
  }
  const int m0 = mx * 256, n0 = ny * 256;
  const u16* gA = A + (size_t)m0 * 1024;
  const u16* gB = Wm + (size_t)n0 * 1024;

  f32x4 acc[8][4] = {};
  bf16x8 af[4][2], bf0[2][2], bf1[2][2];

  // prologue: tile0 all 4 halves -> buf0; tile1 B halves -> buf1; wait tile0 landed (4 loads in flight)
  stageH(LD, 0, 0, 0, gA, 0,  rr, sl8, wv);
  stageH(LD, 0, 0, 1, gA, 0,  rr, sl8, wv);
  stageH(LD, 0, 1, 0, gB, 0,  rr, sl8, wv);
  stageH(LD, 0, 1, 1, gB, 0,  rr, sl8, wv);
  stageH(LD, 1, 1, 0, gB, 64, rr, sl8, wv);
  stageH(LD, 1, 1, 1, gB, 64, rr, sl8, wv);
  asm volatile("s_waitcnt vmcnt(4)" ::: "memory");
  __builtin_amdgcn_s_barrier();

  // 16 K-tiles (K=1024, BK=64); 2 tiles per iter so buffer parity is compile-time
#pragma unroll 1
  for (int t2 = 0; t2 < 7; ++t2) {
    tile16<1, 1, 4>(LD, 0, 2 * t2,     gA, gB, acc, af, bf0, bf1, wr, wc, l15, qd, l7, rr, sl8, wv);
    tile16<1, 1, 4>(LD, 1, 2 * t2 + 1, gA, gB, acc, af, bf0, bf1, wr, wc, l15, qd, l7, rr, sl8, wv);
  }
  tile16<1, 0, 0>(LD, 0, 14, gA, gB, acc, af, bf0, bf1, wr, wc, l15, qd, l7, rr, sl8, wv);
  tile16<0, 0, -1>(LD, 1, 15, gA, gB, acc, af, bf0, bf1, wr, wc, l15, qd, l7, rr, sl8, wv);

  // ---- epilogues ---- C/D layout per 16x16 frag: col = l15, row = qd*4 + r
  // global row = m0 + wr*128 + mi*16 + qd*4 + r ; global col = n0 + wc*64 + ni*16 + l15
  if (mode == 1 && z == 4) {
    if (wc == 0) {
      const float bav = ba[l15], bbv = bb[l15];
#pragma unroll
      for (int mi = 0; mi < 8; ++mi) {
        const int row = m0 + wr * 128 + mi * 16 + qd * 4;
#pragma unroll
        for (int r = 0; r < 4; ++r) {
          al[(size_t)(row + r) * 16 + l15] = sigmoidf_(acc[mi][0][r] + bav);
          be[(size_t)(row + r) * 16 + l15] = sigmoidf_(acc[mi][1][r] + bbv);
        }
      }
    }
    return;
  }
  if (mode == 1 && z <= 1) {
    // l2norm over the head dim: wave's 64 cols = exactly one head (n0, wc*64 both multiples of 64)
#pragma unroll
    for (int mi = 0; mi < 8; ++mi)
#pragma unroll
      for (int r = 0; r < 4; ++r) {
        float ss = acc[mi][0][r] * acc[mi][0][r] + acc[mi][1][r] * acc[mi][1][r]
                 + acc[mi][2][r] * acc[mi][2][r] + acc[mi][3][r] * acc[mi][3][r];
        ss += __shfl_xor(ss, 1); ss += __shfl_xor(ss, 2);
        ss += __shfl_xor(ss, 4); ss += __shfl_xor(ss, 8);
        const float rn = 1.f / fmaxf(sqrtf(ss), 1e-12f);
        acc[mi][0][r] *= rn; acc[mi][1][r] *= rn; acc[mi][2][r] *= rn; acc[mi][3][r] *= rn;
      }
  } else if (mode == 1 && z == 2) {
#pragma unroll
    for (int mi = 0; mi < 8; ++mi)
#pragma unroll
      for (int ni = 0; ni < 4; ++ni)
#pragma unroll
        for (int r = 0; r < 4; ++r)
          acc[mi][ni][r] = acc[mi][ni][r] * sigmoidf_(acc[mi][ni][r]);
  }
  float* C = (mode == 0) ? Cq : ((z == 0) ? Cq : (z == 1) ? Ck : (z == 2) ? Cv : Cg);
#pragma unroll
  for (int mi = 0; mi < 8; ++mi) {
    const int row = m0 + wr * 128 + mi * 16 + qd * 4;
#pragma unroll
    for (int ni = 0; ni < 4; ++ni) {
      const int col = n0 + wc * 64 + ni * 16 + l15;
#pragma unroll
      for (int r = 0; r < 4; ++r)
        C[(size_t)(row + r) * 1024 + col] = acc[mi][ni][r];
    }
  }
}

// ================= chunked scan: row-split waves + shared LDS staging =================
// Block = (bh, chunk-pair). 4 waves: wave wv -> chunk cw=wv>>1 of the pair, row-half = wv&1.
// Wave owns 32 rows x 64 cols; lane: rg=lane>>3 (4-row group), cg=lane&7 (8-col group).
// Tiles of 16 tokens staged to LDS (double-buffered) via global_load_lds, shared by the
// 2 waves of each chunk. Grid = 512 blocks -> 2 blocks/CU -> 2 waves/SIMD.
struct ScanLds1 { float kb[2][2][16 * 64]; float vb[2][2][16 * 64]; float ab[2][2][32]; };
struct ScanLds2 { float kb[2][2][16 * 64]; float qb[2][2][16 * 64]; float vb[2][2][16 * 64]; float ab[2][2][32]; };

// pass 1: compose affine maps over the chunk (Pr/Qr, 4x8 tile per lane)
__global__ __launch_bounds__(256, 2) void scan_p1(const float* __restrict__ k, const float* __restrict__ v,
    const float* __restrict__ al, const float* __restrict__ be,
    float* __restrict__ P, float* __restrict__ Q) {
  __shared__ ScanLds1 L;
  const int tid = threadIdx.x, wv = tid >> 6, lane = tid & 63;
  const int bh = blockIdx.x >> 3, cp = blockIdx.x & 7;
  const int b = bh >> 4, h = bh & 15;
  const int cw = wv >> 1, half = wv & 1;
  const int c = cp * 2 + cw;
  const int rg = lane >> 3, cg = lane & 7;
  const int r0 = half * 32 + rg * 4, c8 = cg * 8;
  const size_t base0[2] = { ((size_t)(b * Sq + (cp * 2 + 0) * LCH)) * 1024 + h * 64,
                            ((size_t)(b * Sq + (cp * 2 + 1) * LCH)) * 1024 + h * 64 };
  const size_t ab0[2]   = { ((size_t)(b * Sq + (cp * 2 + 0) * LCH)) * 16 + h,
                            ((size_t)(b * Sq + (cp * 2 + 1) * LCH)) * 16 + h };
  const int tokw = lane >> 4, seg = lane & 15;
  auto stage = [&](int tile, int bi) {
    #pragma unroll
    for (int j = 0; j < 4; ++j) {        // 16 jobs: (chunk, arr{k,v}, quarter)
      const int job = wv * 4 + j;
      const int ch = job >> 3, rem = job & 7, arr = rem >> 2, i = rem & 3;
      const float* src = arr ? v : k;
      float* dst = arr ? &L.vb[bi][ch][i * 256] : &L.kb[bi][ch][i * 256];
      async16(src + base0[ch] + (size_t)(tile * 16 + i * 4 + tokw) * 1024 + seg * 4, dst);
    }
    if (wv == 0) {                        // a/b: 64 values, one lane each
      const int ch = lane >> 5, w16 = (lane >> 4) & 1, tt = lane & 15;
      const float* s = w16 ? be : al;
      L.ab[bi][ch][w16 * 16 + tt] = s[ab0[ch] + (size_t)(tile * 16 + tt) * 16];
    }
  };
  float Pr[32], Qr[32];
  #pragma unroll
  for (int i = 0; i < 32; ++i) { Pr[i] = 1.f; Qr[i] = 0.f; }
  stage(0, 0);
  for (int tile = 0; tile < 8; ++tile) {
    __syncthreads();
    if (tile < 7) stage(tile + 1, (tile + 1) & 1);
    const int bi = tile & 1;
    const float* kbp = L.kb[bi][cw];
    const float* vbp = L.vb[bi][cw];
    const float* abp = L.ab[bi][cw];
    #pragma unroll 2
    for (int tt = 0; tt < 16; ++tt) {
      const float a = abp[tt], bt = abp[16 + tt];
      float4 kcv0 = *(const float4*)(kbp + tt * 64 + c8);
      float4 kcv1 = *(const float4*)(kbp + tt * 64 + c8 + 4);
      float4 krvv = *(const float4*)(kbp + tt * 64 + r0);
      float4 vrvv = *(const float4*)(vbp + tt * 64 + r0);
      const float kcv[8] = {kcv0.x, kcv0.y, kcv0.z, kcv0.w, kcv1.x, kcv1.y, kcv1.z, kcv1.w};
      const float krv[4] = {krvv.x, krvv.y, krvv.z, krvv.w};
      const float vrv[4] = {vrvv.x, vrvv.y, vrvv.z, vrvv.w};
      const float abt = a * bt;
      float c1[4], c2[4];
      #pragma unroll
      for (int i = 0; i < 4; ++i) { c1[i] = abt * krv[i]; c2[i] = bt * vrv[i]; }
      #pragma unroll
      for (int i = 0; i < 4; ++i)
        #pragma unroll
        for (int j = 0; j < 8; ++j) {
          const int e = i * 8 + j;
          const float A = fmaf(-c1[i], kcv[j], a);
          Qr[e] = fmaf(A, Qr[e], c2[i] * kcv[j]);
          Pr[e] *= A;
        }
    }
  }
  const size_t pbase = ((size_t)bh * CCH + c) * 4096 + (size_t)c8;
  #pragma unroll
  for (int i = 0; i < 4; ++i) {
    const size_t pi = pbase + (size_t)(r0 + i) * 64;
    *(float4*)(P + pi) = make_float4(Pr[i*8],   Pr[i*8+1], Pr[i*8+2], Pr[i*8+3]);
    *(float4*)(P + pi + 4) = make_float4(Pr[i*8+4], Pr[i*8+5], Pr[i*8+6], Pr[i*8+7]);
    *(float4*)(Q + pi) = make_float4(Qr[i*8],   Qr[i*8+1], Qr[i*8+2], Qr[i*8+3]);
    *(float4*)(Q + pi + 4) = make_float4(Qr[i*8+4], Qr[i*8+5], Qr[i*8+6], Qr[i*8+7]);
  }
}

// pass 2: sequential combine over chunks; writes chunk-initial state over P
__global__ __launch_bounds__(256) void scan_comb(float* __restrict__ P, const float* __restrict__ Q) {
  const int g = blockIdx.x * 256 + threadIdx.x;  // 0..262143
  const int elem = g & 4095;
  const int bh = g >> 12;
  float s = 0.f;
  for (int c = 0; c < CCH; ++c) {
    const size_t idx = ((size_t)bh * CCH + c) * 4096 + elem;
    const float p = P[idx], qq = Q[idx];
    P[idx] = s;
    s = fmaf(p, s, qq);
  }
}

// pass 3: re-iterate chunk from s_init, emit outputs
__global__ __launch_bounds__(256, 2) void scan_p2(const float* __restrict__ q, const float* __restrict__ k,
    const float* __restrict__ v, const float* __restrict__ al, const float* __restrict__ be,
    const float* __restrict__ Pini, float* __restrict__ o) {
  __shared__ ScanLds2 L;
  const int tid = threadIdx.x, wv = tid >> 6, lane = tid & 63;
  const int bh = blockIdx.x >> 3, cp = blockIdx.x & 7;
  const int b = bh >> 4, h = bh & 15;
  const int cw = wv >> 1, half = wv & 1;
  const int c = cp * 2 + cw;
  const int rg = lane >> 3, cg = lane & 7;
  const int r0 = half * 32 + rg * 4, c8 = cg * 8;
  const size_t base0[2] = { ((size_t)(b * Sq + (cp * 2 + 0) * LCH)) * 1024 + h * 64,
                            ((size_t)(b * Sq + (cp * 2 + 1) * LCH)) * 1024 + h * 64 };
  const size_t ab0[2]   = { ((size_t)(b * Sq + (cp * 2 + 0) * LCH)) * 16 + h,
                            ((size_t)(b * Sq + (cp * 2 + 1) * LCH)) * 16 + h };
  const size_t mybase = base0[cw];
  const size_t pbase = ((size_t)bh * CCH + c) * 4096 + (size_t)c8;
  const int tokw = lane >> 4, seg = lane & 15;
  auto stage = [&](int tile, int bi) {
    #pragma unroll
    for (int j = 0; j < 6; ++j) {        // 24 jobs: (chunk, arr{k,q,v}, quarter)
      const int job = wv * 6 + j;
      const int ch = job / 12, rem = job % 12, arr = rem >> 2, i = rem & 3;
      const float* src = (arr == 0) ? k : (arr == 1) ? q : v;
      float* dst = (arr == 0) ? &L.kb[bi][ch][i * 256] : (arr == 1) ? &L.qb[bi][ch][i * 256]
                                                                    : &L.vb[bi][ch][i * 256];
      async16(src + base0[ch] + (size_t)(tile * 16 + i * 4 + tokw) * 1024 + seg * 4, dst);
    }
    if (wv == 0) {
      const int ch = lane >> 5, w16 = (lane >> 4) & 1, tt = lane & 15;
      const float* s = w16 ? be : al;
      L.ab[bi][ch][w16 * 16 + tt] = s[ab0[ch] + (size_t)(tile * 16 + tt) * 16];
    }
  };
  float st[32];
  #pragma unroll
  for (int i = 0; i < 4; ++i) {
    float4 s0 = *(const float4*)(Pini + pbase + (size_t)(r0 + i) * 64);
    float4 s1 = *(const float4*)(Pini + pbase + (size_t)(r0 + i) * 64 + 4);
    st[i*8]   = s0.x; st[i*8+1] = s0.y; st[i*8+2] = s0.z; st[i*8+3] = s0.w;
    st[i*8+4] = s1.x; st[i*8+5] = s1.y; st[i*8+6] = s1.z; st[i*8+7] = s1.w;
  }
  stage(0, 0);
  const bool hi4 = (cg & 4), hi2 = (cg & 2);
  const int rowIdx = r0 + (cg >> 1);
  const bool doStore = ((cg & 1) == 0);
  for (int tile = 0; tile < 8; ++tile) {
    __syncthreads();
    if (tile < 7) stage(tile + 1, (tile + 1) & 1);
    const int bi = tile & 1;
    const float* kbp = L.kb[bi][cw];
    const float* qbp = L.qb[bi][cw];
    const float* vbp = L.vb[bi][cw];
    const float* abp = L.ab[bi][cw];
    #pragma unroll 2
    for (int tt = 0; tt < 16; ++tt) {
      const int t = tile * 16 + tt;
      const float a = abp[tt], bt = abp[16 + tt];
      float4 kcv0 = *(const float4*)(kbp + tt * 64 + c8);
      float4 kcv1 = *(const float4*)(kbp + tt * 64 + c8 + 4);
      float4 qcv0 = *(const float4*)(qbp + tt * 64 + c8);
      float4 qcv1 = *(const float4*)(qbp + tt * 64 + c8 + 4);
      float4 krvv = *(const float4*)(kbp + tt * 64 + r0);
      float4 vrvv = *(const float4*)(vbp + tt * 64 + r0);
      const float kcv[8] = {kcv0.x, kcv0.y, kcv0.z, kcv0.w, kcv1.x, kcv1.y, kcv1.z, kcv1.w};
      const float qcv[8] = {qcv0.x, qcv0.y, qcv0.z, qcv0.w, qcv1.x, qcv1.y, qcv1.z, qcv1.w};
      const float krv[4] = {krvv.x, krvv.y, krvv.z, krvv.w};
      const float vrv[4] = {vrvv.x, vrvv.y, vrvv.z, vrvv.w};
      const float abt = a * bt;
      float c1[4], c2[4];
      #pragma unroll
      for (int i = 0; i < 4; ++i) { c1[i] = abt * krv[i]; c2[i] = bt * vrv[i]; }
      float p[4];
      #pragma unroll
      for (int i = 0; i < 4; ++i) p[i] = 0.f;
      #pragma unroll
      for (int i = 0; i < 4; ++i)
        #pragma unroll
        for (int j = 0; j < 8; ++j) {
          const int e = i * 8 + j;
          const float A = fmaf(-c1[i], kcv[j], a);
          st[e] = fmaf(A, st[e], c2[i] * kcv[j]);
          p[i] = fmaf(st[e], qcv[j], p[i]);
        }
      // reduce-scatter over the 8 col-lanes (R5-verified): lane (rg,cg) -> row r0+(cg>>1), even cg stores
      float r2[2];
      #pragma unroll
      for (int i = 0; i < 2; ++i) {
        const float send = hi4 ? p[i] : p[i + 2];
        const float recv = __shfl_xor(send, 4);
        r2[i] = (hi4 ? p[i + 2] : p[i]) + recv;
      }
      float r1;
      {
        const float send = hi2 ? r2[0] : r2[1];
        const float recv = __shfl_xor(send, 2);
        r1 = (hi2 ? r2[1] : r2[0]) + recv;
      }
      const float tot = r1 + __shfl_xor(r1, 1);
      if (doStore) o[mybase + (size_t)t * 1024 + rowIdx] = tot;
    }
  }
}

// ---------------- LayerNorm + silu-gate, write bf16 ----------------
__global__ __launch_bounds__(256) void ln_gate_kernel(const float* __restrict__ o, const float* __restrict__ g,
    const float* __restrict__ ln_g, const float* __restrict__ ln_b, u16* __restrict__ y) {
  const int t = blockIdx.x, tid = threadIdx.x;
  const size_t row = (size_t)t * 1024;
  float4 xv = *(const float4*)(o + row + tid * 4);
  float s  = xv.x + xv.y + xv.z + xv.w;
  float s2 = xv.x * xv.x + xv.y * xv.y + xv.z * xv.z + xv.w * xv.w;
  #pragma unroll
  for (int m = 1; m < 64; m <<= 1) { s += __shfl_xor(s, m); s2 += __shfl_xor(s2, m); }
  __shared__ float red[8];
  const int w = tid >> 6, lane = tid & 63;
  if (lane == 0) { red[w] = s; red[4 + w] = s2; }
  __syncthreads();
  s  = red[0] + red[1] + red[2] + red[3];
  s2 = red[4] + red[5] + red[6] + red[7];
  const float mu = s * (1.f / 1024.f);
  const float var = s2 * (1.f / 1024.f) - mu * mu;
  const float rstd = rsqrtf(var + 1e-5f);
  float4 gv = *(const float4*)(g + row + tid * 4);
  float4 lg = *(const float4*)(ln_g + tid * 4);
  float4 lb = *(const float4*)(ln_b + tid * 4);
  ushort4 u;
  u.x = f2bf(((xv.x - mu) * rstd * lg.x + lb.x) * (gv.x * sigmoidf_(gv.x)));
  u.y = f2bf(((xv.y - mu) * rstd * lg.y + lb.y) * (gv.y * sigmoidf_(gv.y)));
  u.z = f2bf(((xv.z - mu) * rstd * lg.z + lb.z) * (gv.z * sigmoidf_(gv.z)));
  u.w = f2bf(((xv.w - mu) * rstd * lg.w + lb.w) * (gv.w * sigmoidf_(gv.w)));
  *(ushort4*)(y + row + tid * 4) = u;
}

extern "C" void kernel_launch(void* const* d_in, const int* in_sizes, int n_in,
                              void* d_out, int out_size, void* d_ws, size_t ws_size,
                              hipStream_t stream) {
  const float* x    = (const float*)d_in[0];
  const float* Wq   = (const float*)d_in[1];
  const float* Wk   = (const float*)d_in[2];
  const float* Wv   = (const float*)d_in[3];
  const float* Wa   = (const float*)d_in[4];
  const float* ba   = (const float*)d_in[5];
  const float* Wb   = (const float*)d_in[6];
  const float* bb   = (const float*)d_in[7];
  const float* Wg   = (const float*)d_in[8];
  const float* Wo   = (const float*)d_in[9];
  const float* ln_g = (const float*)d_in[10];
  const float* ln_b = (const float*)d_in[11];
  float* out = (float*)d_out;
  char* ws = (char*)d_ws;

  u16*   wb  = (u16*)(ws + OFF_WB);
  u16*   xb  = (u16*)(ws + OFF_XB);   // x-bf16 -> Qc -> y-bf16
  float* qf  = (float*)(ws + OFF_Q);
  float* kf  = (float*)(ws + OFF_K);
  float* vf  = (float*)(ws + OFF_V);
  float* gf  = (float*)(ws + OFF_G);
  float* al  = (float*)(ws + OFF_AL);
  float* be  = (float*)(ws + OFF_BE);
  u16*   wab = (u16*)(ws + OFF_P);    // Wab bf16 (256x1024) during GEMM; region later becomes P
  float* Pb  = (float*)(ws + OFF_P);
  float* Qc  = (float*)(ws + OFF_XB); // reuses dead x-bf16 region
  float* of  = (float*)(ws + OFF_O);
  u16*   yb  = xb;

  cvt_x_kernel<<<8192, 256, 0, stream>>>(x, xb);
  cvt_w_kernel<<<dim3(1024, 1, 5), 256, 0, stream>>>(Wq, Wk, Wv, Wg, Wo, wb);
  cvt_ab_kernel<<<256, 256, 0, stream>>>(Wa, Wb, wab);
  // projections q,k,v,g + alpha/beta: 256x256 8-phase MFMA GEMM, fused epilogues.
  // grid: 32 ab-blocks first, then 4 z x (32 m x 4 n) = 544 blocks of 512 thr (1 block/CU).
  gemm256<<<544, 512, 0, stream>>>(xb, wb, wab, qf, kf, vf, gf, al, be, ba, bb, 1);
  // chunked scan: row-split waves, shared LDS staging, 512 blocks -> 2 blocks/CU
  scan_p1<<<512, 256, 0, stream>>>(kf, vf, al, be, Pb, Qc);
  scan_comb<<<1024, 256, 0, stream>>>(Pb, Qc);
  scan_p2<<<512, 256, 0, stream>>>(qf, kf, vf, al, be, Pb, of);
  // epilogue
  ln_gate_kernel<<<8192, 256, 0, stream>>>(of, gf, ln_g, ln_b, yb);
  gemm256<<<128, 512, 0, stream>>>(yb, wb + (size_t)4 * 1024 * 1024, wab,
                                   out, out, out, out, al, be, ba, bb, 0);
}

// Round 2
// 409.634 us; speedup vs baseline: 1.0915x; 1.0393x over previous
//
#include <hip/hip_runtime.h>

typedef unsigned short u16;
typedef __bf16 bf16x8 __attribute__((ext_vector_type(8)));
typedef float f32x4 __attribute__((ext_vector_type(4)));

constexpr int Bq  = 4;
constexpr int Sq  = 2048;
constexpr int Hq  = 1024;
constexpr int NHq = 16;
constexpr int HDq = 64;
constexpr int CCH = 16;    // chunks
constexpr int LCH = 128;   // chunk length

// workspace layout (bytes), total 212,860,928
constexpr size_t OFF_WB = 0;             // W bf16: 5*1M*2 = 10,485,760
constexpr size_t OFF_XB = 10485760;      // 16,777,216: x-bf16 -> Qc (scan) -> y-bf16 (epilogue)
constexpr size_t OFF_Q  = 27262976;      // q fp32: 33,554,432
constexpr size_t OFF_K  = 60817408;
constexpr size_t OFF_V  = 94371840;
constexpr size_t OFF_G  = 127926272;
constexpr size_t OFF_AL = 161480704;     // alpha: 524,288
constexpr size_t OFF_BE = 162004992;
constexpr size_t OFF_P  = 162529280;     // Wab bf16 (512 KB, 256 rows) during GEMM -> chunk P (16 MB) during scan
constexpr size_t OFF_O  = 179306496;     // of fp32: 33,554,432 (end 212,860,928)

__device__ __forceinline__ u16 f2bf(float f) {
  unsigned u = __float_as_uint(f);
  u += 0x7fffu + ((u >> 16) & 1u);
  return (u16)(u >> 16);
}
__device__ __forceinline__ float sigmoidf_(float x) { return 1.f / (1.f + __expf(-x)); }

__device__ __forceinline__ void async16(const void* g, void* l) {
  __builtin_amdgcn_global_load_lds((const __attribute__((address_space(1))) void*)g,
                                   (__attribute__((address_space(3))) void*)l, 16, 0, 0);
}

// ---------------- converts ----------------
__global__ __launch_bounds__(256) void cvt_x_kernel(const float* __restrict__ in, u16* __restrict__ outp) {
  const size_t i = ((size_t)blockIdx.x * 256 + threadIdx.x) * 4;
  float4 f = *(const float4*)(in + i);
  ushort4 u; u.x = f2bf(f.x); u.y = f2bf(f.y); u.z = f2bf(f.z); u.w = f2bf(f.w);
  *(ushort4*)(outp + i) = u;
}

__global__ __launch_bounds__(256) void cvt_w_kernel(const float* __restrict__ w0, const float* __restrict__ w1,
    const float* __restrict__ w2, const float* __restrict__ w3, const float* __restrict__ w4,
    u16* __restrict__ outp) {
  const int z = blockIdx.z;
  const float* src = (z == 0) ? w0 : (z == 1) ? w1 : (z == 2) ? w2 : (z == 3) ? w3 : w4;
  const size_t i = ((size_t)blockIdx.x * 256 + threadIdx.x) * 4;
  float4 f = *(const float4*)(src + i);
  ushort4 u; u.x = f2bf(f.x); u.y = f2bf(f.y); u.z = f2bf(f.z); u.w = f2bf(f.w);
  *(ushort4*)(outp + (size_t)z * (1024 * 1024) + i) = u;
}

// Wab: 256x1024 bf16; rows 0..15 = Wa, 16..31 = Wb, rest zero (padded for 256-wide B tile)
__global__ __launch_bounds__(256) void cvt_ab_kernel(const float* __restrict__ Wa, const float* __restrict__ Wb,
    u16* __restrict__ outp) {
  const size_t i = ((size_t)blockIdx.x * 256 + threadIdx.x) * 4;
  const int row = (int)(i >> 10);
  ushort4 u;
  if (row < 32) {
    const float* src = (row < 16) ? (Wa + i) : (Wb + i - 16 * 1024);
    float4 f = *(const float4*)src;
    u.x = f2bf(f.x); u.y = f2bf(f.y); u.z = f2bf(f.z); u.w = f2bf(f.w);
  } else {
    u.x = u.y = u.z = u.w = 0;
  }
  *(ushort4*)(outp + i) = u;
}

// ============ 256x256 8-phase bf16 MFMA GEMM (T2+T3+T4+T5) with fused epilogues ============
// 512 thr = 8 waves (2M x 4N); per-wave C = 128x64; BK=64.
// LDS = 2 bufs x {A,B} x 256x64 bf16 = 128 KiB -> 1 block/CU, 2 waves/SIMD.
// T2 swizzle: 16B slot s_phys = s_log ^ (row&7); applied on the gload_lds SOURCE (linear dest)
//   and on the ds_read side -> conflict-free ds_read_b128 (8 accesses/bank = b128 minimum).
// T3/T4 staging (race-free w.r.t. the two-barriers-per-phase structure):
//   tile t: ph0 stages A-h0(t+1)->buf^1, ph1 A-h1(t+1)->buf^1, ph2 B-h0(t+2)->buf, ph3 B-h1(t+2)->buf.
//   B-halves of buf are dead after ph1's closing barrier, A-halves after ph2's -> targets legal.
//   Boundary s_waitcnt vmcnt(4): retires through A-h1(t+1), keeps B(t+2) halves (4 loads) in flight.
// T5: s_setprio(1) around each 16-MFMA cluster. Raw s_barrier everywhere (no compiler vmcnt(0) drain).

__device__ __forceinline__ void lda4(bf16x8 af[4][2], const u16* LA, int wr, int mh, int l15, int qd, int l7) {
#pragma unroll
  for (int i = 0; i < 4; ++i)
#pragma unroll
    for (int kk = 0; kk < 2; ++kk)
      af[i][kk] = *(const bf16x8*)(LA + (wr * 128 + mh * 64 + i * 16 + l15) * 64 + (((kk * 4 + qd) ^ l7) * 8));
}
__device__ __forceinline__ void ldb2(bf16x8 bf[2][2], const u16* LB, int wc, int nh, int l15, int qd, int l7) {
#pragma unroll
  for (int j = 0; j < 2; ++j)
#pragma unroll
    for (int kk = 0; kk < 2; ++kk)
      bf[j][kk] = *(const bf16x8*)(LB + (wc * 64 + nh * 32 + j * 16 + l15) * 64 + (((kk * 4 + qd) ^ l7) * 8));
}
__device__ __forceinline__ void mm16(f32x4 acc[8][4], const bf16x8 af[4][2], const bf16x8 bf[2][2], int mh, int nh) {
#pragma unroll
  for (int i = 0; i < 4; ++i)
#pragma unroll
    for (int j = 0; j < 2; ++j) {
      f32x4 c = acc[mh * 4 + i][nh * 2 + j];
      c = __builtin_amdgcn_mfma_f32_16x16x32_bf16(af[i][0], bf[j][0], c, 0, 0, 0);
      c = __builtin_amdgcn_mfma_f32_16x16x32_bf16(af[i][1], bf[j][1], c, 0, 0, 0);
      acc[mh * 4 + i][nh * 2 + j] = c;
    }
}
// stage one 128x64 half-tile (16 KB) = 2 x global_load_lds(16B) per thread; linear LDS dest,
// inverse-swizzled global source. rr = tid>>3 (row), sl8 = ((tid&7)^(rr&7))*8 (src 16B chunk), wv = tid>>6.
__device__ __forceinline__ void stageH(u16* LD, int bufp, int mat, int h, const u16* gRow0, int kElem,
                                       int rr, int sl8, int wv) {
  const u16* s0 = gRow0 + (size_t)(h * 128 + rr) * 1024 + kElem + sl8;
  u16* d = LD + bufp * 32768 + mat * 16384 + h * 8192 + wv * 512;
  async16(s0, d);
  async16(s0 + (size_t)(64 * 1024), d + 4096);
}

template<int S1, int S2, int VM>
__device__ __forceinline__ void tile16(u16* LD, int bp, int kt,
    const u16* gA, const u16* gB, f32x4 acc[8][4], bf16x8 af[4][2], bf16x8 bf0[2][2], bf16x8 bf1[2][2],
    int wr, int wc, int l15, int qd, int l7, int rr, int sl8, int wv) {
  const u16* LA = LD + bp * 32768;
  const u16* LB = LA + 16384;
  // ---- ph0: quadrant (mh0, nh0); stage A-h0(t+1)
  lda4(af, LA, wr, 0, l15, qd, l7);
  ldb2(bf0, LB, wc, 0, l15, qd, l7);
  if (S1) stageH(LD, bp ^ 1, 0, 0, gA, (kt + 1) * 64, rr, sl8, wv);
  __builtin_amdgcn_s_barrier();
  asm volatile("s_waitcnt lgkmcnt(0)" ::: "memory");
  __builtin_amdgcn_sched_barrier(0);
  __builtin_amdgcn_s_setprio(1);
  mm16(acc, af, bf0, 0, 0);
  __builtin_amdgcn_s_setprio(0);
  __builtin_amdgcn_s_barrier();
  // ---- ph1: (mh0, nh1); stage A-h1(t+1)
  ldb2(bf1, LB, wc, 1, l15, qd, l7);
  if (S1) stageH(LD, bp ^ 1, 0, 1, gA, (kt + 1) * 64, rr, sl8, wv);
  __builtin_amdgcn_s_barrier();
  asm volatile("s_waitcnt lgkmcnt(0)" ::: "memory");
  __builtin_amdgcn_sched_barrier(0);
  __builtin_amdgcn_s_setprio(1);
  mm16(acc, af, bf1, 0, 1);
  __builtin_amdgcn_s_setprio(0);
  __builtin_amdgcn_s_barrier();
  // ---- ph2: (mh1, nh0); stage B-h0(t+2)
  lda4(af, LA, wr, 1, l15, qd, l7);
  if (S2) stageH(LD, bp, 1, 0, gB, (kt + 2) * 64, rr, sl8, wv);
  __builtin_amdgcn_s_barrier();
  asm volatile("s_waitcnt lgkmcnt(0)" ::: "memory");
  __builtin_amdgcn_sched_barrier(0);
  __builtin_amdgcn_s_setprio(1);
  mm16(acc, af, bf0, 1, 0);
  __builtin_amdgcn_s_setprio(0);
  __builtin_amdgcn_s_barrier();
  // ---- ph3: (mh1, nh1); stage B-h1(t+2); boundary counted-vmcnt then barrier
  if (S2) stageH(LD, bp, 1, 1, gB, (kt + 2) * 64, rr, sl8, wv);
  __builtin_amdgcn_s_barrier();
  __builtin_amdgcn_sched_barrier(0);
  __builtin_amdgcn_s_setprio(1);
  mm16(acc, af, bf1, 1, 1);
  __builtin_amdgcn_s_setprio(0);
  if (VM == 4) asm volatile("s_waitcnt vmcnt(4)" ::: "memory");
  else if (VM == 0) asm volatile("s_waitcnt vmcnt(0)" ::: "memory");
  __builtin_amdgcn_s_barrier();
}

// mode 0: plain store to Cq (final out-proj).
// mode 1: blocks 0..31 -> alpha/beta (Wab, sigmoid+bias, wc==0 stores); blocks 32.. -> z = q,k,v,g
//         with fused l2norm/l2norm/silu/plain epilogues.
__global__ __launch_bounds__(512, 2) void gemm256(const u16* __restrict__ A, const u16* __restrict__ Wall,
    const u16* __restrict__ Wab,
    float* __restrict__ Cq, float* __restrict__ Ck, float* __restrict__ Cv, float* __restrict__ Cg,
    float* __restrict__ al, float* __restrict__ be,
    const float* __restrict__ ba, const float* __restrict__ bb, int mode) {
  __shared__ __align__(16) u16 Lds[65536];   // 128 KiB: [buf][A|B][256][64] bf16
  u16* LD = &Lds[0];
  const int tid = threadIdx.x;
  const int wv = tid >> 6, lane = tid & 63;
  const int l15 = lane & 15, qd = lane >> 4, l7 = l15 & 7;
  const int wr = wv >> 2, wc = wv & 3;
  const int rr = tid >> 3, sl8 = ((tid & 7) ^ (rr & 7)) * 8;

  int mx, ny, z;
  const u16* Wm;
  if (mode == 0) { mx = blockIdx.x & 31; ny = blockIdx.x >> 5; z = 0; Wm = Wall; }
  else if (blockIdx.x < 32) { mx = blockIdx.x; ny = 0; z = 4; Wm = Wab; }
  else {
    const int b = blockIdx.x - 32;
    mx = b & 31; ny = (b >> 5) & 3; z = b >> 7;
    Wm = Wall + (size_t)z * (1024 * 1024);
  }
  const int m0 = mx * 256, n0 = ny * 256;
  const u16* gA = A + (size_t)m0 * 1024;
  const u16* gB = Wm + (size_t)n0 * 1024;

  f32x4 acc[8][4] = {};
  bf16x8 af[4][2], bf0[2][2], bf1[2][2];

  // prologue: tile0 all 4 halves -> buf0; tile1 B halves -> buf1; wait tile0 landed (4 loads in flight)
  stageH(LD, 0, 0, 0, gA, 0,  rr, sl8, wv);
  stageH(LD, 0, 0, 1, gA, 0,  rr, sl8, wv);
  stageH(LD, 0, 1, 0, gB, 0,  rr, sl8, wv);
  stageH(LD, 0, 1, 1, gB, 0,  rr, sl8, wv);
  stageH(LD, 1, 1, 0, gB, 64, rr, sl8, wv);
  stageH(LD, 1, 1, 1, gB, 64, rr, sl8, wv);
  asm volatile("s_waitcnt vmcnt(4)" ::: "memory");
  __builtin_amdgcn_s_barrier();

  // 16 K-tiles (K=1024, BK=64); 2 tiles per iter so buffer parity is compile-time
#pragma unroll 1
  for (int t2 = 0; t2 < 7; ++t2) {
    tile16<1, 1, 4>(LD, 0, 2 * t2,     gA, gB, acc, af, bf0, bf1, wr, wc, l15, qd, l7, rr, sl8, wv);
    tile16<1, 1, 4>(LD, 1, 2 * t2 + 1, gA, gB, acc, af, bf0, bf1, wr, wc, l15, qd, l7, rr, sl8, wv);
  }
  tile16<1, 0, 0>(LD, 0, 14, gA, gB, acc, af, bf0, bf1, wr, wc, l15, qd, l7, rr, sl8, wv);
  tile16<0, 0, -1>(LD, 1, 15, gA, gB, acc, af, bf0, bf1, wr, wc, l15, qd, l7, rr, sl8, wv);

  // ---- epilogues ---- C/D layout per 16x16 frag: col = l15, row = qd*4 + r
  // global row = m0 + wr*128 + mi*16 + qd*4 + r ; global col = n0 + wc*64 + ni*16 + l15
  if (mode == 1 && z == 4) {
    if (wc == 0) {
      const float bav = ba[l15], bbv = bb[l15];
#pragma unroll
      for (int mi = 0; mi < 8; ++mi) {
        const int row = m0 + wr * 128 + mi * 16 + qd * 4;
#pragma unroll
        for (int r = 0; r < 4; ++r) {
          al[(size_t)(row + r) * 16 + l15] = sigmoidf_(acc[mi][0][r] + bav);
          be[(size_t)(row + r) * 16 + l15] = sigmoidf_(acc[mi][1][r] + bbv);
        }
      }
    }
    return;
  }
  if (mode == 1 && z <= 1) {
    // l2norm over the head dim: wave's 64 cols = exactly one head (n0, wc*64 both multiples of 64)
#pragma unroll
    for (int mi = 0; mi < 8; ++mi)
#pragma unroll
      for (int r = 0; r < 4; ++r) {
        float ss = acc[mi][0][r] * acc[mi][0][r] + acc[mi][1][r] * acc[mi][1][r]
                 + acc[mi][2][r] * acc[mi][2][r] + acc[mi][3][r] * acc[mi][3][r];
        ss += __shfl_xor(ss, 1); ss += __shfl_xor(ss, 2);
        ss += __shfl_xor(ss, 4); ss += __shfl_xor(ss, 8);
        const float rn = 1.f / fmaxf(sqrtf(ss), 1e-12f);
        acc[mi][0][r] *= rn; acc[mi][1][r] *= rn; acc[mi][2][r] *= rn; acc[mi][3][r] *= rn;
      }
  } else if (mode == 1 && z == 2) {
#pragma unroll
    for (int mi = 0; mi < 8; ++mi)
#pragma unroll
      for (int ni = 0; ni < 4; ++ni)
#pragma unroll
        for (int r = 0; r < 4; ++r)
          acc[mi][ni][r] = acc[mi][ni][r] * sigmoidf_(acc[mi][ni][r]);
  }
  float* C = (mode == 0) ? Cq : ((z == 0) ? Cq : (z == 1) ? Ck : (z == 2) ? Cv : Cg);
#pragma unroll
  for (int mi = 0; mi < 8; ++mi) {
    const int row = m0 + wr * 128 + mi * 16 + qd * 4;
#pragma unroll
    for (int ni = 0; ni < 4; ++ni) {
      const int col = n0 + wc * 64 + ni * 16 + l15;
#pragma unroll
      for (int r = 0; r < 4; ++r)
        C[(size_t)(row + r) * 1024 + col] = acc[mi][ni][r];
    }
  }
}

// ================= chunked scan: 1 chunk/block, 4 row-split waves (4 blocks/CU) =================
// Block = (bh, chunk). 4 waves: wave wv owns rows wv*16..wv*16+15 of the 64x64 state.
// Lane: rg=lane>>3 (2-row group), cg=lane&7 (8-col group) -> 16 state elems/lane.
// Tiles of 16 tokens staged to LDS (double-buffered) via global_load_lds, shared by all 4 waves.
// Grid = 1024 blocks -> 4 blocks/CU -> 4 waves/SIMD (VGPR<=128 via launch_bounds).
struct ScanLds1 { float kb[2][16 * 64]; float vb[2][16 * 64]; float ab[2][32]; };
struct ScanLds2 { float kb[2][16 * 64]; float qb[2][16 * 64]; float vb[2][16 * 64]; float ab[2][32]; };

// pass 1: compose affine maps over the chunk (Pr/Qr, 2x8 tile per lane)
__global__ __launch_bounds__(256, 4) void scan_p1(const float* __restrict__ k, const float* __restrict__ v,
    const float* __restrict__ al, const float* __restrict__ be,
    float* __restrict__ P, float* __restrict__ Q) {
  __shared__ ScanLds1 L;
  const int tid = threadIdx.x, wv = tid >> 6, lane = tid & 63;
  const int bh = blockIdx.x >> 4, c = blockIdx.x & 15;
  const int b = bh >> 4, h = bh & 15;
  const int rg = lane >> 3, cg = lane & 7;
  const int r0 = wv * 16 + rg * 2, c8 = cg * 8;
  const size_t base0 = ((size_t)(b * Sq + c * LCH)) * 1024 + h * 64;
  const size_t ab0   = ((size_t)(b * Sq + c * LCH)) * 16 + h;
  const int tokw = lane >> 4, seg = lane & 15;
  auto stage = [&](int tile, int bi) {
    #pragma unroll
    for (int j = 0; j < 2; ++j) {        // 8 jobs: (arr{k,v}, quarter)
      const int job = wv * 2 + j;
      const int arr = job >> 2, i = job & 3;
      const float* src = arr ? v : k;
      float* dst = arr ? &L.vb[bi][i * 256] : &L.kb[bi][i * 256];
      async16(src + base0 + (size_t)(tile * 16 + i * 4 + tokw) * 1024 + seg * 4, dst);
    }
    if (wv == 0 && lane < 32) {          // a/b: 32 values, one lane each
      const int w16 = lane >> 4, tt = lane & 15;
      const float* s = w16 ? be : al;
      L.ab[bi][w16 * 16 + tt] = s[ab0 + (size_t)(tile * 16 + tt) * 16];
    }
  };
  float Pr[16], Qr[16];
  #pragma unroll
  for (int i = 0; i < 16; ++i) { Pr[i] = 1.f; Qr[i] = 0.f; }
  stage(0, 0);
  for (int tile = 0; tile < 8; ++tile) {
    __syncthreads();
    if (tile < 7) stage(tile + 1, (tile + 1) & 1);
    const int bi = tile & 1;
    const float* kbp = L.kb[bi];
    const float* vbp = L.vb[bi];
    const float* abp = L.ab[bi];
    #pragma unroll 2
    for (int tt = 0; tt < 16; ++tt) {
      const float a = abp[tt], bt = abp[16 + tt];
      float4 kcv0 = *(const float4*)(kbp + tt * 64 + c8);
      float4 kcv1 = *(const float4*)(kbp + tt * 64 + c8 + 4);
      float2 krvv = *(const float2*)(kbp + tt * 64 + r0);
      float2 vrvv = *(const float2*)(vbp + tt * 64 + r0);
      const float kcv[8] = {kcv0.x, kcv0.y, kcv0.z, kcv0.w, kcv1.x, kcv1.y, kcv1.z, kcv1.w};
      const float krv[2] = {krvv.x, krvv.y};
      const float vrv[2] = {vrvv.x, vrvv.y};
      const float abt = a * bt;
      float c1[2], c2[2];
      #pragma unroll
      for (int i = 0; i < 2; ++i) { c1[i] = abt * krv[i]; c2[i] = bt * vrv[i]; }
      #pragma unroll
      for (int i = 0; i < 2; ++i)
        #pragma unroll
        for (int j = 0; j < 8; ++j) {
          const int e = i * 8 + j;
          const float A = fmaf(-c1[i], kcv[j], a);
          Qr[e] = fmaf(A, Qr[e], c2[i] * kcv[j]);
          Pr[e] *= A;
        }
    }
  }
  const size_t pbase = ((size_t)bh * CCH + c) * 4096 + (size_t)c8;
  #pragma unroll
  for (int i = 0; i < 2; ++i) {
    const size_t pi = pbase + (size_t)(r0 + i) * 64;
    *(float4*)(P + pi)     = make_float4(Pr[i*8],   Pr[i*8+1], Pr[i*8+2], Pr[i*8+3]);
    *(float4*)(P + pi + 4) = make_float4(Pr[i*8+4], Pr[i*8+5], Pr[i*8+6], Pr[i*8+7]);
    *(float4*)(Q + pi)     = make_float4(Qr[i*8],   Qr[i*8+1], Qr[i*8+2], Qr[i*8+3]);
    *(float4*)(Q + pi + 4) = make_float4(Qr[i*8+4], Qr[i*8+5], Qr[i*8+6], Qr[i*8+7]);
  }
}

// pass 2: sequential combine over chunks; writes chunk-initial state over P
__global__ __launch_bounds__(256) void scan_comb(float* __restrict__ P, const float* __restrict__ Q) {
  const int g = blockIdx.x * 256 + threadIdx.x;  // 0..262143
  const int elem = g & 4095;
  const int bh = g >> 12;
  float s = 0.f;
  for (int c = 0; c < CCH; ++c) {
    const size_t idx = ((size_t)bh * CCH + c) * 4096 + elem;
    const float p = P[idx], qq = Q[idx];
    P[idx] = s;
    s = fmaf(p, s, qq);
  }
}

// pass 3: re-iterate chunk from s_init, emit outputs
__global__ __launch_bounds__(256, 4) void scan_p2(const float* __restrict__ q, const float* __restrict__ k,
    const float* __restrict__ v, const float* __restrict__ al, const float* __restrict__ be,
    const float* __restrict__ Pini, float* __restrict__ o) {
  __shared__ ScanLds2 L;
  const int tid = threadIdx.x, wv = tid >> 6, lane = tid & 63;
  const int bh = blockIdx.x >> 4, c = blockIdx.x & 15;
  const int b = bh >> 4, h = bh & 15;
  const int rg = lane >> 3, cg = lane & 7;
  const int r0 = wv * 16 + rg * 2, c8 = cg * 8;
  const size_t base0 = ((size_t)(b * Sq + c * LCH)) * 1024 + h * 64;
  const size_t ab0   = ((size_t)(b * Sq + c * LCH)) * 16 + h;
  const size_t pbase = ((size_t)bh * CCH + c) * 4096 + (size_t)c8;
  const int tokw = lane >> 4, seg = lane & 15;
  auto stage = [&](int tile, int bi) {
    #pragma unroll
    for (int j = 0; j < 3; ++j) {        // 12 jobs: (arr{k,q,v}, quarter)
      const int job = wv * 3 + j;
      const int arr = job >> 2, i = job & 3;
      const float* src = (arr == 0) ? k : (arr == 1) ? q : v;
      float* dst = (arr == 0) ? &L.kb[bi][i * 256] : (arr == 1) ? &L.qb[bi][i * 256]
                                                                : &L.vb[bi][i * 256];
      async16(src + base0 + (size_t)(tile * 16 + i * 4 + tokw) * 1024 + seg * 4, dst);
    }
    if (wv == 0 && lane < 32) {
      const int w16 = lane >> 4, tt = lane & 15;
      const float* s = w16 ? be : al;
      L.ab[bi][w16 * 16 + tt] = s[ab0 + (size_t)(tile * 16 + tt) * 16];
    }
  };
  float st[16];
  #pragma unroll
  for (int i = 0; i < 2; ++i) {
    float4 s0 = *(const float4*)(Pini + pbase + (size_t)(r0 + i) * 64);
    float4 s1 = *(const float4*)(Pini + pbase + (size_t)(r0 + i) * 64 + 4);
    st[i*8]   = s0.x; st[i*8+1] = s0.y; st[i*8+2] = s0.z; st[i*8+3] = s0.w;
    st[i*8+4] = s1.x; st[i*8+5] = s1.y; st[i*8+6] = s1.z; st[i*8+7] = s1.w;
  }
  stage(0, 0);
  const bool hi4 = (cg & 4);
  const int rowIdx = r0 + (cg >> 2);
  const bool doStore = ((cg & 3) == 0);
  for (int tile = 0; tile < 8; ++tile) {
    __syncthreads();
    if (tile < 7) stage(tile + 1, (tile + 1) & 1);
    const int bi = tile & 1;
    const float* kbp = L.kb[bi];
    const float* qbp = L.qb[bi];
    const float* vbp = L.vb[bi];
    const float* abp = L.ab[bi];
    #pragma unroll 2
    for (int tt = 0; tt < 16; ++tt) {
      const int t = tile * 16 + tt;
      const float a = abp[tt], bt = abp[16 + tt];
      float4 kcv0 = *(const float4*)(kbp + tt * 64 + c8);
      float4 kcv1 = *(const float4*)(kbp + tt * 64 + c8 + 4);
      float4 qcv0 = *(const float4*)(qbp + tt * 64 + c8);
      float4 qcv1 = *(const float4*)(qbp + tt * 64 + c8 + 4);
      float2 krvv = *(const float2*)(kbp + tt * 64 + r0);
      float2 vrvv = *(const float2*)(vbp + tt * 64 + r0);
      const float kcv[8] = {kcv0.x, kcv0.y, kcv0.z, kcv0.w, kcv1.x, kcv1.y, kcv1.z, kcv1.w};
      const float qcv[8] = {qcv0.x, qcv0.y, qcv0.z, qcv0.w, qcv1.x, qcv1.y, qcv1.z, qcv1.w};
      const float krv[2] = {krvv.x, krvv.y};
      const float vrv[2] = {vrvv.x, vrvv.y};
      const float abt = a * bt;
      float c1[2], c2[2];
      #pragma unroll
      for (int i = 0; i < 2; ++i) { c1[i] = abt * krv[i]; c2[i] = bt * vrv[i]; }
      float p[2];
      p[0] = 0.f; p[1] = 0.f;
      #pragma unroll
      for (int i = 0; i < 2; ++i)
        #pragma unroll
        for (int j = 0; j < 8; ++j) {
          const int e = i * 8 + j;
          const float A = fmaf(-c1[i], kcv[j], a);
          st[e] = fmaf(A, st[e], c2[i] * kcv[j]);
          p[i] = fmaf(st[e], qcv[j], p[i]);
        }
      // reduce over the 8 col-lanes: keep-one/send-one split at xor4, then xor2/xor1.
      // lanes cg 0..3 end with row r0's total, cg 4..7 with row r0+1's; cg 0 and 4 store.
      float my    = hi4 ? p[1] : p[0];
      float other = hi4 ? p[0] : p[1];
      my += __shfl_xor(other, 4);
      my += __shfl_xor(my, 2);
      my += __shfl_xor(my, 1);
      if (doStore) o[base0 + (size_t)t * 1024 + rowIdx] = my;
    }
  }
}

// ---------------- LayerNorm + silu-gate, write bf16 ----------------
__global__ __launch_bounds__(256) void ln_gate_kernel(const float* __restrict__ o, const float* __restrict__ g,
    const float* __restrict__ ln_g, const float* __restrict__ ln_b, u16* __restrict__ y) {
  const int t = blockIdx.x, tid = threadIdx.x;
  const size_t row = (size_t)t * 1024;
  float4 xv = *(const float4*)(o + row + tid * 4);
  float s  = xv.x + xv.y + xv.z + xv.w;
  float s2 = xv.x * xv.x + xv.y * xv.y + xv.z * xv.z + xv.w * xv.w;
  #pragma unroll
  for (int m = 1; m < 64; m <<= 1) { s += __shfl_xor(s, m); s2 += __shfl_xor(s2, m); }
  __shared__ float red[8];
  const int w = tid >> 6, lane = tid & 63;
  if (lane == 0) { red[w] = s; red[4 + w] = s2; }
  __syncthreads();
  s  = red[0] + red[1] + red[2] + red[3];
  s2 = red[4] + red[5] + red[6] + red[7];
  const float mu = s * (1.f / 1024.f);
  const float var = s2 * (1.f / 1024.f) - mu * mu;
  const float rstd = rsqrtf(var + 1e-5f);
  float4 gv = *(const float4*)(g + row + tid * 4);
  float4 lg = *(const float4*)(ln_g + tid * 4);
  float4 lb = *(const float4*)(ln_b + tid * 4);
  ushort4 u;
  u.x = f2bf(((xv.x - mu) * rstd * lg.x + lb.x) * (gv.x * sigmoidf_(gv.x)));
  u.y = f2bf(((xv.y - mu) * rstd * lg.y + lb.y) * (gv.y * sigmoidf_(gv.y)));
  u.z = f2bf(((xv.z - mu) * rstd * lg.z + lb.z) * (gv.z * sigmoidf_(gv.z)));
  u.w = f2bf(((xv.w - mu) * rstd * lg.w + lb.w) * (gv.w * sigmoidf_(gv.w)));
  *(ushort4*)(y + row + tid * 4) = u;
}

extern "C" void kernel_launch(void* const* d_in, const int* in_sizes, int n_in,
                              void* d_out, int out_size, void* d_ws, size_t ws_size,
                              hipStream_t stream) {
  const float* x    = (const float*)d_in[0];
  const float* Wq   = (const float*)d_in[1];
  const float* Wk   = (const float*)d_in[2];
  const float* Wv   = (const float*)d_in[3];
  const float* Wa   = (const float*)d_in[4];
  const float* ba   = (const float*)d_in[5];
  const float* Wb   = (const float*)d_in[6];
  const float* bb   = (const float*)d_in[7];
  const float* Wg   = (const float*)d_in[8];
  const float* Wo   = (const float*)d_in[9];
  const float* ln_g = (const float*)d_in[10];
  const float* ln_b = (const float*)d_in[11];
  float* out = (float*)d_out;
  char* ws = (char*)d_ws;

  u16*   wb  = (u16*)(ws + OFF_WB);
  u16*   xb  = (u16*)(ws + OFF_XB);   // x-bf16 -> Qc -> y-bf16
  float* qf  = (float*)(ws + OFF_Q);
  float* kf  = (float*)(ws + OFF_K);
  float* vf  = (float*)(ws + OFF_V);
  float* gf  = (float*)(ws + OFF_G);
  float* al  = (float*)(ws + OFF_AL);
  float* be  = (float*)(ws + OFF_BE);
  u16*   wab = (u16*)(ws + OFF_P);    // Wab bf16 (256x1024) during GEMM; region later becomes P
  float* Pb  = (float*)(ws + OFF_P);
  float* Qc  = (float*)(ws + OFF_XB); // reuses dead x-bf16 region
  float* of  = (float*)(ws + OFF_O);
  u16*   yb  = xb;

  cvt_x_kernel<<<8192, 256, 0, stream>>>(x, xb);
  cvt_w_kernel<<<dim3(1024, 1, 5), 256, 0, stream>>>(Wq, Wk, Wv, Wg, Wo, wb);
  cvt_ab_kernel<<<256, 256, 0, stream>>>(Wa, Wb, wab);
  // projections q,k,v,g + alpha/beta: 256x256 8-phase MFMA GEMM, fused epilogues.
  // grid: 32 ab-blocks first, then 4 z x (32 m x 4 n) = 544 blocks of 512 thr (1 block/CU).
  gemm256<<<544, 512, 0, stream>>>(xb, wb, wab, qf, kf, vf, gf, al, be, ba, bb, 1);
  // chunked scan: 1 chunk/block, 4 row-split waves, 1024 blocks -> 4 blocks/CU
  scan_p1<<<1024, 256, 0, stream>>>(kf, vf, al, be, Pb, Qc);
  scan_comb<<<1024, 256, 0, stream>>>(Pb, Qc);
  scan_p2<<<1024, 256, 0, stream>>>(qf, kf, vf, al, be, Pb, of);
  // epilogue
  ln_gate_kernel<<<8192, 256, 0, stream>>>(of, gf, ln_g, ln_b, yb);
  gemm256<<<128, 512, 0, stream>>>(yb, wb + (size_t)4 * 1024 * 1024, wab,
                                   out, out, out, out, al, be, ba, bb, 0);
}